// Round 13
// baseline (574.331 us; speedup 1.0000x reference)
//
#include <hip/hip_runtime.h>
#include <hip/hip_cooperative_groups.h>

namespace cg = cooperative_groups;

// Problem constants
#define V_  32000
#define E_  256
#define H_  256
#define S_  128
#define B_  64
#define HID_ 30

typedef float f32x2 __attribute__((ext_vector_type(2)));

// Fast activations (v_exp_f32 + v_rcp_f32; ~3e-7 abs err). Round-1/7 evidence:
// LSTM-path precision changes do not move absmax (identical 0.0004882812).
__device__ __forceinline__ float sigmoid_fast(float x) {
    return __builtin_amdgcn_rcpf(1.f + __expf(-x));
}
__device__ __forceinline__ float fast_tanh(float x) {
    return 1.f - 2.f * __builtin_amdgcn_rcpf(1.f + __expf(2.f * x));
}
__device__ __forceinline__ float sigmoid_acc(float x) {
    return 1.0f / (1.0f + expf(-x));
}

// Fast-path exchange ops (64-bit scalar operands -> VGPR pairs).
// NOTE gfx950 assembler syntax: offset: immediate must precede cache flags.
// Producer: two plain dwordx2 stores (write-through L1 -> home XCD L2).
// Consumer: two sc0 loads (L1 bypass, reads shared XCD L2), one waitcnt.
//
// POLL STRUCTURE IS LOAD-BEARING (r1, r7 post-mortems): the serial
// fast-pair-then-slow-pair loop, both checked EVERY iteration, is the only
// cadence that has not regressed. Do not restructure.
// DOT NOTE (r10): h-quad LDS reads are same-address BROADCAST (cheap);
// readlane broadcast regressed. SETPRIO (r11): neutral, removed.
__device__ __forceinline__ void store_l2x2(unsigned long long* p,
                                           unsigned long long a,
                                           unsigned long long b) {
    asm volatile("global_store_dwordx2 %2, %0, off\n\t"
                 "global_store_dwordx2 %2, %1, off offset:8"
                 :: "v"(a), "v"(b), "v"(p) : "memory");
}
__device__ __forceinline__ void load_l2x2(const unsigned long long* p,
                                          unsigned long long& a,
                                          unsigned long long& b) {
    asm volatile("global_load_dwordx2 %0, %2, off sc0\n\t"
                 "global_load_dwordx2 %1, %2, off offset:8 sc0\n\t"
                 "s_waitcnt vmcnt(0)"
                 : "=&v"(a), "=&v"(b) : "v"(p) : "memory");
}

// LDS-only barrier: orders LDS (h buffer) across the WG WITHOUT the vmcnt(0)
// drain __syncthreads() emits.
__device__ __forceinline__ void barrier_lds() {
    asm volatile("s_waitcnt lgkmcnt(0)" ::: "memory");
    __builtin_amdgcn_s_barrier();
    __builtin_amdgcn_sched_barrier(0);
}

// ---------------------------------------------------------------------------
// K2 (FUSED): prologue = prep (sT build + Fch/Sch zero) + input-projection
// GEMM (Xg = emb @ Wih^T, 128x512 tile per WG) -> grid.sync() -> LSTM
// recurrence (r12/r9-exact). Eliminates 2 dispatches and the cooperative
// drain boundary after gemm2 -- r12 accounting showed ~170us of the 271us
// non-lstm time is not kernel work.
//
// Recurrence (unchanged): K-split pair, dual-path exchange, 256 WGs x 512thr,
// 1 WG/CU, w: side=w>>7 (partner w^128), P=w&127, dir=P&1, b=P>>1.
// Weights: pairs 0..37 regs (asm-pinned), 38..55 LDS float4-interleaved,
// 56..63 regs (hoisted). One LDS-only barrier/step, h double-buffered,
// f/o handoff via __shfl_xor(.,32). Poll: serial dual-path, both checked
// every iteration.
// ---------------------------------------------------------------------------
#define RP_  38
#define LPD_ 18

__global__ __launch_bounds__(512)
__attribute__((amdgpu_waves_per_eu(2, 2)))
void lstm_fused_kernel(
    const int* __restrict__ concepts,      // [S][B]
    const float* __restrict__ embedding,   // [V][E]
    const float* __restrict__ Wih_f, const float* __restrict__ Wih_b,
    float* __restrict__ Xg,                // [2][8192][1024]
    const float* __restrict__ Whh_f, const float* __restrict__ Whh_b,
    const float* __restrict__ b_f, const float* __restrict__ b_b,
    const int* __restrict__ lens,
    float* __restrict__ enc,               // [B][S][512]
    unsigned long long* __restrict__ Fch,  // [P=128][2 par][2 prodside][512]
    unsigned long long* __restrict__ Sch,  // same; contiguous after Fch
    float4* __restrict__ sT) {             // [16][1024]
    extern __shared__ float4 Wl4[];   // recurrence: [LPD_][512]; prologue: As/Bs
    __shared__ float h_sh[2][128];    // double-buffered own-side h (read s&1)
    const int w = blockIdx.x;
    const int t = threadIdx.x;

    // ---------------- PROLOGUE 1: prep share (sT + channel zero) -----------
    if (t < 64) {
        int i = (w << 6) + t;                 // 0..16383
        int r = i & 1023;
        int q = i >> 10;                      // 0..15
        int jq = q & 3;
        int sideq = (q >> 2) & 1;
        int dirq = q >> 3;
        const float* WhhQ = dirq ? Whh_b : Whh_f;
        const float* src = WhhQ + (size_t)r * H_ + sideq * 128 + 112 + 4 * jq;
        sT[(size_t)q * 1024 + r] = make_float4(src[0], src[1], src[2], src[3]);
    }
#pragma unroll
    for (int i = 0; i < 4; ++i)               // Fch+Sch contiguous: 524288 ull
        Fch[(size_t)w * 2048 + t + 512 * i] = 0ull;

    // ---------------- PROLOGUE 2: input-projection GEMM --------------------
    // WG w: rowblk = w>>1 (0..127), colhalf = w&1. dir = rowblk>>6,
    // m0 = (rowblk&63)*128 rows, n0 = colhalf*512 cols. 128x512 tile,
    // 512 thr x (8 rows x 16 cols), KC=32 via LDS (aliased into Wl4 region).
    {
        const int rowblk = w >> 1;
        const int chg = w & 1;
        const int dirg = rowblk >> 6;
        const int m0 = (rowblk & 63) * 128;
        const int n0 = chg * 512;
        const float* WihG = dirg ? Wih_b : Wih_f;
        float* As_ = (float*)Wl4;             // [32][132] = 16.9KB
        float* Bs_ = As_ + 32 * 132;          // [32][516] = 66KB  (83KB < 147KB)

        int cidg[2];
#pragma unroll
        for (int i = 0; i < 2; ++i) {
            int flat = t + 512 * i;
            cidg[i] = concepts[m0 + (flat >> 3)];
        }
        const int tmg = (t & 15) * 4;         // row group
        const int tng = (t >> 4) * 16;        // col group (0..496)

        f32x2 accg[8][8];
#pragma unroll
        for (int i = 0; i < 8; ++i)
#pragma unroll
            for (int j = 0; j < 8; ++j) accg[i][j] = (f32x2){0.f, 0.f};

        for (int kk = 0; kk < E_; kk += 32) {
            __syncthreads();
            // stage A (embedding gather): 2 float4/thread
#pragma unroll
            for (int i = 0; i < 2; ++i) {
                int flat = t + 512 * i;
                int r = flat >> 3;            // 0..127
                int kq = (flat & 7) * 4;
                float4 av = *(const float4*)&embedding[(size_t)cidg[i] * E_ + kk + kq];
                As_[(kq + 0) * 132 + r] = av.x; As_[(kq + 1) * 132 + r] = av.y;
                As_[(kq + 2) * 132 + r] = av.z; As_[(kq + 3) * 132 + r] = av.w;
            }
            // stage B (Wih rows n0..n0+511): 8 float4/thread
#pragma unroll
            for (int i = 0; i < 8; ++i) {
                int flat = t + 512 * i;
                int r = flat >> 3;            // 0..511
                int kq = (flat & 7) * 4;
                float4 bv = *(const float4*)&WihG[(size_t)(n0 + r) * E_ + kk + kq];
                Bs_[(kq + 0) * 516 + r] = bv.x; Bs_[(kq + 1) * 516 + r] = bv.y;
                Bs_[(kq + 2) * 516 + r] = bv.z; Bs_[(kq + 3) * 516 + r] = bv.w;
            }
            __syncthreads();
#pragma unroll
            for (int k = 0; k < 32; ++k) {
                float4 a0 = *(const float4*)&As_[k * 132 + tmg];
                float4 a1 = *(const float4*)&As_[k * 132 + tmg + 64];
                float am[8] = {a0.x, a0.y, a0.z, a0.w, a1.x, a1.y, a1.z, a1.w};
                float4 b0 = *(const float4*)&Bs_[k * 516 + tng];
                float4 b1 = *(const float4*)&Bs_[k * 516 + tng + 4];
                float4 b2 = *(const float4*)&Bs_[k * 516 + tng + 8];
                float4 b3 = *(const float4*)&Bs_[k * 516 + tng + 12];
                f32x2 bn2[8] = {(f32x2){b0.x, b0.y}, (f32x2){b0.z, b0.w},
                                (f32x2){b1.x, b1.y}, (f32x2){b1.z, b1.w},
                                (f32x2){b2.x, b2.y}, (f32x2){b2.z, b2.w},
                                (f32x2){b3.x, b3.y}, (f32x2){b3.z, b3.w}};
#pragma unroll
                for (int i = 0; i < 8; ++i) {
                    f32x2 ai = (f32x2){am[i], am[i]};
#pragma unroll
                    for (int j = 0; j < 8; ++j)
                        accg[i][j] = __builtin_elementwise_fma(ai, bn2[j], accg[i][j]);
                }
            }
        }
        float* outg = Xg + ((size_t)dirg * 8192 + m0) * 1024 + n0;
#pragma unroll
        for (int i = 0; i < 8; ++i) {
            int mr = (i < 4) ? (tmg + i) : (tmg + 60 + i);
#pragma unroll
            for (int j2 = 0; j2 < 4; ++j2)
                *(float4*)&outg[(size_t)mr * 1024 + tng + 4 * j2] =
                    make_float4(accg[i][2 * j2].x, accg[i][2 * j2].y,
                                accg[i][2 * j2 + 1].x, accg[i][2 * j2 + 1].y);
        }
    }

    // grid-wide sync: Xg/sT/Fch visible to all WGs (agent-scope fences)
    cg::this_grid().sync();

    // ---------------- RECURRENCE (r12/r9-exact) ----------------------------
    const int side = w >> 7;
    const int P = w & 127;
    const int dir = P & 1, b = P >> 1;
    const int wav = t >> 6;
    const int lane = t & 63;
    const int li = lane & 31;
    const int half = lane >> 5;                    // 0:(i,g)  1:(f,o)
    const int qw = (wav & 1) | ((wav >> 2) << 1);  // 0..3 within cons/prod set
    const bool mine = (((wav >> 1) & 1) == side);  // consumer wave (uniform)
    const int hs = mine ? side : (side ^ 1);       // side of h-cols served
    const int hcol = (hs << 7) + (qw << 5) + li;   // h column 0..255
    const int rA = hcol + half * 256;              // i- or f-gate row
    const int rB = hcol + 512 + half * 256;        // g- or o-gate row
    const int base = side << 7;
    const int idx = (qw << 6) + lane;              // exchange slot 0..255
    const float* Whh = dir ? Whh_b : Whh_f;
    const int len = lens[b];

    // pin weights: rows rA, rB, own-side pair-cols [0,38) in regs
    f32x2 w0[RP_], w1[RP_];
    {
        const f32x2* p0 = (const f32x2*)(Whh + (size_t)rA * H_ + base);
        const f32x2* p1 = (const f32x2*)(Whh + (size_t)rB * H_ + base);
#pragma unroll
        for (int j = 0; j < RP_; ++j) { w0[j] = p0[j]; w1[j] = p1[j]; }
        // pairs [38,56) in LDS, rA/rB interleaved -> one b128 per pair
#pragma unroll
        for (int j = 0; j < LPD_; ++j) {
            f32x2 a = p0[RP_ + j], c2 = p1[RP_ + j];
            Wl4[j * 512 + t] = make_float4(a.x, a.y, c2.x, c2.y);
        }
    }
    // pairs 56..63: loop-invariant, pinned in regs as f32x2 (8 per row)
    const f32x2* sT2 = (const f32x2*)(sT + (size_t)(dir * 8 + side * 4) * 1024);
    f32x2 s0[8], s1[8];
#pragma unroll
    for (int k = 0; k < 4; ++k) {
        s0[2 * k]     = sT2[2 * (k * 1024 + rA)];
        s0[2 * k + 1] = sT2[2 * (k * 1024 + rA) + 1];
        s1[2 * k]     = sT2[2 * (k * 1024 + rB)];
        s1[2 * k + 1] = sT2[2 * (k * 1024 + rB) + 1];
    }
    // Keep pinned values live in the register file across the whole loop.
    // NOTE: 64-bit f32x2 ties compile; 128-bit float4 ties do not (r5).
#pragma unroll
    for (int j = 0; j < RP_; ++j) {
        asm volatile("" : "+v"(w0[j]), "+v"(w1[j]));
    }
#pragma unroll
    for (int k = 0; k < 8; ++k) {
        asm volatile("" : "+v"(s0[k]), "+v"(s1[k]));
    }
    const float* bias = dir ? b_b : b_f;
    const float bias0 = bias[rA], bias1 = bias[rB];

    // exchange base pointers (parity applied per step via +1024 elements)
    unsigned long long* fwb = Fch + (((size_t)P * 2 + 0) * 2 + side) * 512 + 2 * idx;
    const unsigned long long* frb =
        Fch + (((size_t)P * 2 + 0) * 2 + (side ^ 1)) * 512 + 2 * idx;
    unsigned long long* swb = Sch + (((size_t)P * 2 + 0) * 2 + side) * 512 + 2 * idx;
    const unsigned long long* srb =
        Sch + (((size_t)P * 2 + 0) * 2 + (side ^ 1)) * 512 + 2 * idx;

    if (t < 128) h_sh[0][t] = 0.f;
    float c = 0.f;                    // cell state (consumer lanes 0..31)
    __syncthreads();                  // full sync once (Wl4 + h init)

    // x prefetch (consumers only)
    int srow = dir ? (len - 1) : 0;   // len >= 1 guaranteed
    float x0 = 0.f, x1 = 0.f;
    if (mine) {
        const float* xp = Xg + ((size_t)dir * 8192 + (size_t)srow * B_ + b) * 1024;
        x0 = xp[rA]; x1 = xp[rB];
    }

    for (int s = 0; s < S_; ++s) {
        // next-step x prefetch
        int srow_n = 0;
        float x0n = 0.f, x1n = 0.f;
        if (s + 1 < S_) {
            int ns = s + 1;
            srow_n = dir ? ((ns < len) ? (len - 1 - ns) : ns) : ns;
            if (mine) {
                const float* xp =
                    Xg + ((size_t)dir * 8192 + (size_t)srow_n * B_ + b) * 1024;
                x0n = xp[rA]; x1n = xp[rB];
            }
        }

        // partial dot over own side's 128 cols, rows rA and rB
        const float4* hb4 = (const float4*)h_sh[s & 1];
        f32x2 a0 = (f32x2){0.f, 0.f}, a1 = (f32x2){0.f, 0.f};
        // REG phase: pairs 0..37, h quads 0..18
#pragma unroll
        for (int q = 0; q < 19; ++q) {
            float4 hq = hb4[q];
            f32x2 hA = (f32x2){hq.x, hq.y}, hB = (f32x2){hq.z, hq.w};
            a0 = __builtin_elementwise_fma(w0[2 * q], hA, a0);
            a0 = __builtin_elementwise_fma(w0[2 * q + 1], hB, a0);
            a1 = __builtin_elementwise_fma(w1[2 * q], hA, a1);
            a1 = __builtin_elementwise_fma(w1[2 * q + 1], hB, a1);
        }
        // LDS phase: pairs 38..55 (one b128 each), h quads 19..27
#pragma unroll
        for (int jj = 0; jj < 9; ++jj) {
            float4 hq = hb4[19 + jj];
            f32x2 hA = (f32x2){hq.x, hq.y}, hB = (f32x2){hq.z, hq.w};
            float4 wE = Wl4[(2 * jj) * 512 + t];       // pair 38+2jj
            float4 wO = Wl4[(2 * jj + 1) * 512 + t];   // pair 39+2jj
            a0 = __builtin_elementwise_fma((f32x2){wE.x, wE.y}, hA, a0);
            a1 = __builtin_elementwise_fma((f32x2){wE.z, wE.w}, hA, a1);
            a0 = __builtin_elementwise_fma((f32x2){wO.x, wO.y}, hB, a0);
            a1 = __builtin_elementwise_fma((f32x2){wO.z, wO.w}, hB, a1);
        }
        // REG-stream phase: pairs 56..63, h quads 28..31
#pragma unroll
        for (int k = 0; k < 4; ++k) {
            float4 hq = hb4[28 + k];
            f32x2 hA = (f32x2){hq.x, hq.y}, hB = (f32x2){hq.z, hq.w};
            a0 = __builtin_elementwise_fma(s0[2 * k], hA, a0);
            a0 = __builtin_elementwise_fma(s0[2 * k + 1], hB, a0);
            a1 = __builtin_elementwise_fma(s1[2 * k], hA, a1);
            a1 = __builtin_elementwise_fma(s1[2 * k + 1], hB, a1);
        }
        float p0 = a0.x + a0.y, p1 = a1.x + a1.y;

        const unsigned tag = (unsigned)(s + 1);
        const size_t par = (size_t)(s & 1) << 10;   // parity offset (elements)
        if (!mine) {
            unsigned long long k0 =
                ((unsigned long long)tag << 32) | (unsigned long long)__float_as_uint(p0);
            unsigned long long k1 =
                ((unsigned long long)tag << 32) | (unsigned long long)__float_as_uint(p1);
            // fast path: two plain 8B stores, same 16B line (XCD L2)
            store_l2x2(fwb + par, k0, k1);
            // slow path: LLC-coherent packed atomics (placement-safe);
            // never waited on -- producers have no per-step vmcnt waits
            unsigned long long* sb = swb + par;
            __hip_atomic_store(sb, k0, __ATOMIC_RELAXED, __HIP_MEMORY_SCOPE_AGENT);
            __hip_atomic_store(sb + 1, k1, __ATOMIC_RELAXED, __HIP_MEMORY_SCOPE_AGENT);
        } else {
            const unsigned long long* fr = frb + par;
            const unsigned long long* sr = srb + par;
            float q0f, q1f;
            for (;;) {
                unsigned long long f0, f1;
                load_l2x2(fr, f0, f1);
                if ((unsigned)(f0 >> 32) == tag && (unsigned)(f1 >> 32) == tag) {
                    q0f = __uint_as_float((unsigned)f0);
                    q1f = __uint_as_float((unsigned)f1);
                    break;
                }
                unsigned long long a0q = __hip_atomic_load(
                    sr, __ATOMIC_RELAXED, __HIP_MEMORY_SCOPE_AGENT);
                unsigned long long a1q = __hip_atomic_load(
                    sr + 1, __ATOMIC_RELAXED, __HIP_MEMORY_SCOPE_AGENT);
                if ((unsigned)(a0q >> 32) == tag && (unsigned)(a1q >> 32) == tag) {
                    q0f = __uint_as_float((unsigned)a0q);
                    q1f = __uint_as_float((unsigned)a1q);
                    break;
                }
            }
            float g0 = p0 + q0f + bias0 + x0;
            float g1 = p1 + q1f + bias1 + x1;
            // half 0: g0=i-gate, g1=g-gate; half 1: g0=f-gate, g1=o-gate
            float e0 = sigmoid_fast(g0);
            float u, v;
            if (half == 0) { u = e0 * fast_tanh(g1); v = 0.f; }  // u = i*g
            else           { u = e0; v = sigmoid_fast(g1); }     // u = f, v = o
            float fx = __shfl_xor(u, 32);   // lanes<32 receive f
            float ox = __shfl_xor(v, 32);   // lanes<32 receive o
            if (half == 0) {
                c = fx * c + u;
                float h = ox * fast_tanh(c);
                h_sh[(s + 1) & 1][(qw << 5) + li] = h;
                int orow = dir ? srow : s;
                enc[((size_t)b * S_ + orow) * 512 + dir * H_ + base + (qw << 5) + li] =
                    (orow < len) ? h : 0.f;
            }
        }
        // ONE barrier per step, LDS-only wait: h(s+1) published; no vmcnt drain
        barrier_lds();

        srow = srow_n;
        x0 = x0n; x1 = x1n;
    }
}

// ---------------------------------------------------------------------------
// K3: U = enc@Ua^T, W = enc@Wa^T  (r12: grid (8,64), 16 rows/block)
// ---------------------------------------------------------------------------
__global__ __launch_bounds__(256) void uw_kernel(
    const float* __restrict__ enc, const float* __restrict__ Ua,
    const float* __restrict__ Wa, float* __restrict__ U, float* __restrict__ Wout) {
    __shared__ float wgt[60][129];
    __shared__ float erow[4][128];
    const int tid = threadIdx.x;
    const int b = blockIdx.y, s0 = blockIdx.x * 16;
    const int rl = tid >> 6;
    const int d = tid & 63;
    const int dd = d & 31;
    const int isW = d >> 5;
    float acc[4];
#pragma unroll
    for (int i = 0; i < 4; ++i) acc[i] = 0.f;

    for (int kk = 0; kk < 4; ++kk) {
        __syncthreads();
        for (int i = tid; i < 30 * 128; i += 256) {
            int r = i >> 7, k = i & 127;
            wgt[r][k] = Ua[(size_t)r * 512 + kk * 128 + k];
            wgt[r + 30][k] = Wa[(size_t)r * 512 + kk * 128 + k];
        }
        for (int chunk = 0; chunk < 4; ++chunk) {
            __syncthreads();
            for (int i = tid; i < 4 * 128; i += 256) {
                int r = i >> 7, k = i & 127;
                erow[r][k] = enc[((size_t)b * S_ + (s0 + chunk * 4 + r)) * 512 + kk * 128 + k];
            }
            __syncthreads();
            if (dd < HID_) {
                const float* wr = wgt[dd + 30 * isW];
                const float* er = erow[rl];
                float a = acc[chunk];
#pragma unroll
                for (int k = 0; k < 128; ++k) a = fmaf(er[k], wr[k], a);
                acc[chunk] = a;
            }
        }
    }
    if (dd < HID_) {
        float* dst = isW ? Wout : U;
#pragma unroll
        for (int chunk = 0; chunk < 4; ++chunk)
            dst[((size_t)b * S_ + (s0 + chunk * 4 + rl)) * 32 + dd] = acc[chunk];
    }
}

// ---------------------------------------------------------------------------
// K4: scores + predictions  (r12: grid (8,64), 16 i-rows/block)
// ---------------------------------------------------------------------------
__global__ __launch_bounds__(256) void scores_kernel(
    const float* __restrict__ U, const float* __restrict__ W,
    const float* __restrict__ va,
    float* __restrict__ scores, float* __restrict__ preds) {
    __shared__ float w_sh[128][31];
    const int b = blockIdx.y, i0 = blockIdx.x * 16;
    const int tid = threadIdx.x;

    float va_r[HID_];
#pragma unroll
    for (int d2 = 0; d2 < HID_; ++d2) va_r[d2] = va[d2];

    for (int i = tid; i < 128 * HID_; i += 256) {
        int r = i / HID_, d2 = i - r * HID_;
        w_sh[r][d2] = W[((size_t)b * S_ + r) * 32 + d2];
    }
    __syncthreads();

    const int il = tid >> 4;            // 0..15
    const int jb = (tid & 15) * 8;      // 0..120
    float u_r[HID_];
    const float* urow = U + ((size_t)b * S_ + i0 + il) * 32;
#pragma unroll
    for (int d2 = 0; d2 < HID_; ++d2) u_r[d2] = urow[d2];

    const size_t obase = ((size_t)b * S_ + (i0 + il)) * S_;
    for (int jj = 0; jj < 8; ++jj) {
        int j = jb + jj;
        float acc = 0.f;
#pragma unroll
        for (int d2 = 0; d2 < HID_; ++d2)
            acc = fmaf(va_r[d2], fast_tanh(u_r[d2] + w_sh[j][d2]), acc);
        scores[obase + j] = acc;
        preds[obase + j] = (sigmoid_acc(acc) >= 0.5f) ? 1.f : 0.f;
    }
}

// ---------------------------------------------------------------------------
// Workspace layout (bytes):
//   Xg   @ 0          : 2*8192*1024*4 = 67,108,864
//   enc  @ 67,108,864 : 64*128*512*4  = 16,777,216
//   U    @ 83,886,080 : 8192*32*4     =  1,048,576
//   W    @ 84,934,656 : 8192*32*4     =  1,048,576
//   Fch  @ 85,983,232 : 128*2*2*512*8 =  2,097,152
//   Sch  @ 88,080,384 : 128*2*2*512*8 =  2,097,152
//   sT   @ 90,177,536 : 16*1024*16    =    262,144   (total ~90.4 MB)
// ---------------------------------------------------------------------------
extern "C" void kernel_launch(void* const* d_in, const int* in_sizes, int n_in,
                              void* d_out, int out_size, void* d_ws, size_t ws_size,
                              hipStream_t stream) {
    (void)in_sizes; (void)n_in; (void)out_size; (void)ws_size;
    const int* concepts = (const int*)d_in[0];
    const int* lens = (const int*)d_in[1];
    const float* embedding = (const float*)d_in[2];
    const float* Wih_f = (const float*)d_in[3];
    const float* Whh_f = (const float*)d_in[4];
    const float* b_f = (const float*)d_in[5];
    const float* Wih_b = (const float*)d_in[6];
    const float* Whh_b = (const float*)d_in[7];
    const float* b_b = (const float*)d_in[8];
    const float* Ua = (const float*)d_in[9];
    const float* Wa = (const float*)d_in[10];
    const float* va = (const float*)d_in[11];

    char* ws = (char*)d_ws;
    float* Xg = (float*)(ws + 0);
    float* enc = (float*)(ws + 67108864);
    float* U = (float*)(ws + 83886080);
    float* W = (float*)(ws + 84934656);
    unsigned long long* Fch = (unsigned long long*)(ws + 85983232);
    unsigned long long* Sch = (unsigned long long*)(ws + 88080384);
    float4* sT = (float4*)(ws + 90177536);

    float* scores = (float*)d_out;
    float* preds = scores + (size_t)B_ * S_ * S_;

    // single cooperative dispatch: prep + gemm + grid.sync + recurrence
    {
        void* ka[] = {(void*)&concepts, (void*)&embedding, (void*)&Wih_f,
                      (void*)&Wih_b, (void*)&Xg, (void*)&Whh_f, (void*)&Whh_b,
                      (void*)&b_f, (void*)&b_b, (void*)&lens, (void*)&enc,
                      (void*)&Fch, (void*)&Sch, (void*)&sT};
        (void)hipLaunchCooperativeKernel((const void*)lstm_fused_kernel,
                                         dim3(256), dim3(512), ka,
                                         LPD_ * 512 * sizeof(float4), stream);
    }

    hipLaunchKernelGGL(uw_kernel, dim3(8, 64), dim3(256), 0, stream,
                       enc, Ua, Wa, U, W);
    hipLaunchKernelGGL(scores_kernel, dim3(8, 64), dim3(256), 0, stream,
                       U, W, va, scores, preds);
}

// Round 14
// 484.366 us; speedup vs baseline: 1.1857x; 1.1857x over previous
//
#include <hip/hip_runtime.h>

// Problem constants
#define V_  32000
#define E_  256
#define H_  256
#define S_  128
#define B_  64
#define HID_ 30

typedef float f32x2 __attribute__((ext_vector_type(2)));
typedef float f32x4v __attribute__((ext_vector_type(4)));
typedef _Float16 f16x4 __attribute__((ext_vector_type(4)));
typedef _Float16 f16x8 __attribute__((ext_vector_type(8)));

// Fast activations (v_exp_f32 + v_rcp_f32; ~3e-7 abs err). Round-1/7 evidence:
// LSTM-path precision changes do not move absmax (identical 0.0004882812).
__device__ __forceinline__ float sigmoid_fast(float x) {
    return __builtin_amdgcn_rcpf(1.f + __expf(-x));
}
__device__ __forceinline__ float fast_tanh(float x) {
    return 1.f - 2.f * __builtin_amdgcn_rcpf(1.f + __expf(2.f * x));
}
__device__ __forceinline__ float sigmoid_acc(float x) {
    return 1.0f / (1.0f + expf(-x));
}

// Fast-path exchange ops (64-bit scalar operands -> VGPR pairs).
// NOTE gfx950 assembler syntax: offset: immediate must precede cache flags.
// Producer: two plain dwordx2 stores (write-through L1 -> home XCD L2).
// Consumer: two sc0 loads (L1 bypass, reads shared XCD L2), one waitcnt.
//
// POLL STRUCTURE IS LOAD-BEARING (r1, r7 post-mortems): the serial
// fast-pair-then-slow-pair loop, both checked EVERY iteration, is the only
// cadence that has not regressed. Do not restructure.
// DOT NOTE (r10): h-quad LDS reads are same-address BROADCAST (cheap);
// readlane broadcast regressed. SETPRIO (r11): neutral. FUSION (r13):
// regressed -- gemm needs 16 waves/CU, recurrence needs 1 WG/CU; keep split.
__device__ __forceinline__ void store_l2x2(unsigned long long* p,
                                           unsigned long long a,
                                           unsigned long long b) {
    asm volatile("global_store_dwordx2 %2, %0, off\n\t"
                 "global_store_dwordx2 %2, %1, off offset:8"
                 :: "v"(a), "v"(b), "v"(p) : "memory");
}
__device__ __forceinline__ void load_l2x2(const unsigned long long* p,
                                          unsigned long long& a,
                                          unsigned long long& b) {
    asm volatile("global_load_dwordx2 %0, %2, off sc0\n\t"
                 "global_load_dwordx2 %1, %2, off offset:8 sc0\n\t"
                 "s_waitcnt vmcnt(0)"
                 : "=&v"(a), "=&v"(b) : "v"(p) : "memory");
}

// LDS-only barrier: orders LDS (h buffer) across the WG WITHOUT the vmcnt(0)
// drain __syncthreads() emits.
__device__ __forceinline__ void barrier_lds() {
    asm volatile("s_waitcnt lgkmcnt(0)" ::: "memory");
    __builtin_amdgcn_s_barrier();
    __builtin_amdgcn_sched_barrier(0);
}

// ---------------------------------------------------------------------------
// K0: prep. (a) build sT (last 16 cols 112..127 of each Whh row, transposed;
// plane q = dir*8+side*4+j); (b) zero Fch+Sch (4MB contiguous); (c) convert
// embedding and Wih_f/Wih_b to f16 for the MFMA gemm. embF16 aliases the enc
// region (written by lstm AFTER gemm2 reads it); WihF16 aliases U (written
// by uw after gemm2). grid 256 x 256 thr.
// ---------------------------------------------------------------------------
__global__ __launch_bounds__(256) void prep_stream_kernel(
    const float* __restrict__ Whh_f, const float* __restrict__ Whh_b,
    const float* __restrict__ embedding,
    const float* __restrict__ Wih_f, const float* __restrict__ Wih_b,
    float4* __restrict__ sT, unsigned long long* __restrict__ Fch,
    _Float16* __restrict__ embF16, _Float16* __restrict__ WihF16) {
    const int gtid = blockIdx.x * 256 + threadIdx.x;   // 0..65535
    if (gtid < 16 * 1024) {
        int r = gtid & 1023;
        int q = gtid >> 10;                   // 0..15
        int jq = q & 3;
        int side = (q >> 2) & 1;
        int dir = q >> 3;
        const float* Whh = dir ? Whh_b : Whh_f;
        const float* src = Whh + (size_t)r * H_ + side * 128 + 112 + 4 * jq;
        sT[(size_t)q * 1024 + r] = make_float4(src[0], src[1], src[2], src[3]);
    }
    // zero Fch+Sch: 524288 ullongs / 65536 threads = 8 each
#pragma unroll
    for (int i = 0; i < 8; ++i) Fch[(size_t)gtid + 65536 * i] = 0ull;

    // embedding f32 -> f16: 2,048,000 float4s
    const float4* e4 = (const float4*)embedding;
    for (int k4 = gtid; k4 < 2048000; k4 += 65536) {
        float4 v = e4[k4];
        *(f16x4*)(embF16 + 4 * (size_t)k4) =
            (f16x4){(_Float16)v.x, (_Float16)v.y, (_Float16)v.z, (_Float16)v.w};
    }
    // Wih_f / Wih_b f32 -> f16: 65536 float4s each (one per thread)
    {
        float4 v = ((const float4*)Wih_f)[gtid];
        *(f16x4*)(WihF16 + 4 * (size_t)gtid) =
            (f16x4){(_Float16)v.x, (_Float16)v.y, (_Float16)v.z, (_Float16)v.w};
        float4 u = ((const float4*)Wih_b)[gtid];
        *(f16x4*)(WihF16 + 262144 + 4 * (size_t)gtid) =
            (f16x4){(_Float16)u.x, (_Float16)u.y, (_Float16)u.z, (_Float16)u.w};
    }
}

// ---------------------------------------------------------------------------
// K1: input-projection GEMM on the MATRIX cores (r14).
// r13 data: fp32-VALU gemm2 was ~120-130us (8.6 GFLOP at 46% of the 157TF
// vector peak -- the 55us fp32 floor made VALU the wrong unit). f16 MFMA
// (mfma_f32_16x16x32_f16, fp32 accum): quantization error ~1.4e-5 on gate
// preacts, well under the 4.88e-4 absmax floor.
// Correctness: A and B frags use the IDENTICAL per-lane k-mapping (8
// consecutive k at (lane>>4)*8), so any intra-lane k-permutation cancels by
// dot symmetry; C/D layout is HW-verified: col=lane&15, row=(lane>>4)*4+reg.
// Tiling: grid (512,2) = 64 M-tiles x 8 N-tiles x 2 dirs; WG 256thr = 4
// waves; wave v owns rows 32v..32v+31 (2 row-tiles) x 128 cols (8 col-tiles)
// = 16 MFMA tiles, K=256 in 8 chunks of 32. No LDS -- frags straight from
// L2-resident f16 arrays.
// ---------------------------------------------------------------------------
__global__ __launch_bounds__(256, 4) void gemm2_kernel(
    const int* __restrict__ concepts, const _Float16* __restrict__ embF16,
    const _Float16* __restrict__ WihF16, float* __restrict__ Xg) {
    const int dir = blockIdx.y;
    const _Float16* WihF = WihF16 + (size_t)dir * 262144;
    const int mt = blockIdx.x >> 3;
    const int nt = blockIdx.x & 7;
    const int m0 = mt * 128, n0 = nt * 128;
    const int t = threadIdx.x;
    const int v = t >> 6;
    const int lane = t & 63;
    const int lr = lane & 15;          // A-row / B-col within 16x16 tile
    const int kg = lane >> 4;          // k-group 0..3
    const int ko = kg * 8;             // k-offset within 32-chunk

    const int cid0 = concepts[m0 + 32 * v + lr];
    const int cid1 = concepts[m0 + 32 * v + 16 + lr];
    const _Float16* a0p = embF16 + (size_t)cid0 * 256 + ko;
    const _Float16* a1p = embF16 + (size_t)cid1 * 256 + ko;
    const _Float16* bp = WihF + (size_t)(n0 + lr) * 256 + ko;

    f32x4v acc[2][8];
#pragma unroll
    for (int i = 0; i < 2; ++i)
#pragma unroll
        for (int j = 0; j < 8; ++j) acc[i][j] = (f32x4v){0.f, 0.f, 0.f, 0.f};

#pragma unroll
    for (int kk = 0; kk < 256; kk += 32) {
        f16x8 af0 = *(const f16x8*)(a0p + kk);
        f16x8 af1 = *(const f16x8*)(a1p + kk);
#pragma unroll
        for (int ct = 0; ct < 8; ++ct) {
            f16x8 bf = *(const f16x8*)(bp + ct * 4096 + kk);
            acc[0][ct] = __builtin_amdgcn_mfma_f32_16x16x32_f16(
                af0, bf, acc[0][ct], 0, 0, 0);
            acc[1][ct] = __builtin_amdgcn_mfma_f32_16x16x32_f16(
                af1, bf, acc[1][ct], 0, 0, 0);
        }
    }
    // D: col = n0+16ct+lr, row (local) = 16rb + kg*4 + r
    float* outp = Xg + ((size_t)dir * 8192 + m0 + 32 * v) * 1024 + n0 + lr;
#pragma unroll
    for (int rb = 0; rb < 2; ++rb)
#pragma unroll
        for (int ct = 0; ct < 8; ++ct)
#pragma unroll
            for (int r = 0; r < 4; ++r)
                outp[(size_t)(16 * rb + kg * 4 + r) * 1024 + 16 * ct] =
                    acc[rb][ct][r];
}

// ---------------------------------------------------------------------------
// K2: LSTM, K-split pair with dual-path (L2-fast + LLC-safe) exchange.
// r12/r9-EXACT (best measured: 257.4-260us). 256 WGs x 512 thr (1 WG/CU),
// cooperative. w: side=w>>7 (partner w^128), P=w&127, dir=P&1, b=P>>1.
// Weights: pairs 0..37 regs (asm-pinned), 38..55 LDS float4-interleaved,
// 56..63 regs (hoisted). One LDS-only barrier/step, h double-buffered,
// f/o handoff via __shfl_xor(.,32). Poll: serial dual-path every iteration.
// ---------------------------------------------------------------------------
#define RP_  38
#define LPD_ 18

__global__ __launch_bounds__(512)
__attribute__((amdgpu_waves_per_eu(2, 2)))
void lstm_ks3_kernel(
    const float* __restrict__ Xg,     // [2][8192][1024]
    const float* __restrict__ Whh_f, const float* __restrict__ Whh_b,
    const float* __restrict__ b_f, const float* __restrict__ b_b,
    const int* __restrict__ lens,
    float* __restrict__ enc,          // [B][S][512]
    unsigned long long* __restrict__ Fch,  // [P=128][2 par][2 prodside][512]
    unsigned long long* __restrict__ Sch,  // same; contiguous after Fch
    const float4* __restrict__ sT) {  // [16][1024]
    extern __shared__ float4 Wl4[];   // [LPD_][512]
    __shared__ float h_sh[2][128];    // double-buffered own-side h (read s&1)
    const int w = blockIdx.x;
    const int side = w >> 7;
    const int P = w & 127;
    const int dir = P & 1, b = P >> 1;
    const int t = threadIdx.x;
    const int wav = t >> 6;
    const int lane = t & 63;
    const int li = lane & 31;
    const int half = lane >> 5;                    // 0:(i,g)  1:(f,o)
    const int qw = (wav & 1) | ((wav >> 2) << 1);  // 0..3 within cons/prod set
    const bool mine = (((wav >> 1) & 1) == side);  // consumer wave (uniform)
    const int hs = mine ? side : (side ^ 1);       // side of h-cols served
    const int hcol = (hs << 7) + (qw << 5) + li;   // h column 0..255
    const int rA = hcol + half * 256;              // i- or f-gate row
    const int rB = hcol + 512 + half * 256;        // g- or o-gate row
    const int base = side << 7;
    const int idx = (qw << 6) + lane;              // exchange slot 0..255
    const float* Whh = dir ? Whh_b : Whh_f;
    const int len = lens[b];

    // pin weights: rows rA, rB, own-side pair-cols [0,38) in regs
    f32x2 w0[RP_], w1[RP_];
    {
        const f32x2* p0 = (const f32x2*)(Whh + (size_t)rA * H_ + base);
        const f32x2* p1 = (const f32x2*)(Whh + (size_t)rB * H_ + base);
#pragma unroll
        for (int j = 0; j < RP_; ++j) { w0[j] = p0[j]; w1[j] = p1[j]; }
        // pairs [38,56) in LDS, rA/rB interleaved -> one b128 per pair
#pragma unroll
        for (int j = 0; j < LPD_; ++j) {
            f32x2 a = p0[RP_ + j], c2 = p1[RP_ + j];
            Wl4[j * 512 + t] = make_float4(a.x, a.y, c2.x, c2.y);
        }
    }
    // pairs 56..63: loop-invariant, pinned in regs as f32x2 (8 per row)
    const f32x2* sT2 = (const f32x2*)(sT + (size_t)(dir * 8 + side * 4) * 1024);
    f32x2 s0[8], s1[8];
#pragma unroll
    for (int k = 0; k < 4; ++k) {
        s0[2 * k]     = sT2[2 * (k * 1024 + rA)];
        s0[2 * k + 1] = sT2[2 * (k * 1024 + rA) + 1];
        s1[2 * k]     = sT2[2 * (k * 1024 + rB)];
        s1[2 * k + 1] = sT2[2 * (k * 1024 + rB) + 1];
    }
    // Keep pinned values live in the register file across the whole loop.
    // NOTE: 64-bit f32x2 ties compile; 128-bit float4 ties do not (r5).
#pragma unroll
    for (int j = 0; j < RP_; ++j) {
        asm volatile("" : "+v"(w0[j]), "+v"(w1[j]));
    }
#pragma unroll
    for (int k = 0; k < 8; ++k) {
        asm volatile("" : "+v"(s0[k]), "+v"(s1[k]));
    }
    const float* bias = dir ? b_b : b_f;
    const float bias0 = bias[rA], bias1 = bias[rB];

    // exchange base pointers (parity applied per step via +1024 elements)
    unsigned long long* fwb = Fch + (((size_t)P * 2 + 0) * 2 + side) * 512 + 2 * idx;
    const unsigned long long* frb =
        Fch + (((size_t)P * 2 + 0) * 2 + (side ^ 1)) * 512 + 2 * idx;
    unsigned long long* swb = Sch + (((size_t)P * 2 + 0) * 2 + side) * 512 + 2 * idx;
    const unsigned long long* srb =
        Sch + (((size_t)P * 2 + 0) * 2 + (side ^ 1)) * 512 + 2 * idx;

    if (t < 128) h_sh[0][t] = 0.f;
    float c = 0.f;                    // cell state (consumer lanes 0..31)
    __syncthreads();                  // full sync once (Wl4 + h init)

    // x prefetch (consumers only)
    int srow = dir ? (len - 1) : 0;   // len >= 1 guaranteed
    float x0 = 0.f, x1 = 0.f;
    if (mine) {
        const float* xp = Xg + ((size_t)dir * 8192 + (size_t)srow * B_ + b) * 1024;
        x0 = xp[rA]; x1 = xp[rB];
    }

    for (int s = 0; s < S_; ++s) {
        // next-step x prefetch
        int srow_n = 0;
        float x0n = 0.f, x1n = 0.f;
        if (s + 1 < S_) {
            int ns = s + 1;
            srow_n = dir ? ((ns < len) ? (len - 1 - ns) : ns) : ns;
            if (mine) {
                const float* xp =
                    Xg + ((size_t)dir * 8192 + (size_t)srow_n * B_ + b) * 1024;
                x0n = xp[rA]; x1n = xp[rB];
            }
        }

        // partial dot over own side's 128 cols, rows rA and rB
        const float4* hb4 = (const float4*)h_sh[s & 1];
        f32x2 a0 = (f32x2){0.f, 0.f}, a1 = (f32x2){0.f, 0.f};
        // REG phase: pairs 0..37, h quads 0..18
#pragma unroll
        for (int q = 0; q < 19; ++q) {
            float4 hq = hb4[q];
            f32x2 hA = (f32x2){hq.x, hq.y}, hB = (f32x2){hq.z, hq.w};
            a0 = __builtin_elementwise_fma(w0[2 * q], hA, a0);
            a0 = __builtin_elementwise_fma(w0[2 * q + 1], hB, a0);
            a1 = __builtin_elementwise_fma(w1[2 * q], hA, a1);
            a1 = __builtin_elementwise_fma(w1[2 * q + 1], hB, a1);
        }
        // LDS phase: pairs 38..55 (one b128 each), h quads 19..27
#pragma unroll
        for (int jj = 0; jj < 9; ++jj) {
            float4 hq = hb4[19 + jj];
            f32x2 hA = (f32x2){hq.x, hq.y}, hB = (f32x2){hq.z, hq.w};
            float4 wE = Wl4[(2 * jj) * 512 + t];       // pair 38+2jj
            float4 wO = Wl4[(2 * jj + 1) * 512 + t];   // pair 39+2jj
            a0 = __builtin_elementwise_fma((f32x2){wE.x, wE.y}, hA, a0);
            a1 = __builtin_elementwise_fma((f32x2){wE.z, wE.w}, hA, a1);
            a0 = __builtin_elementwise_fma((f32x2){wO.x, wO.y}, hB, a0);
            a1 = __builtin_elementwise_fma((f32x2){wO.z, wO.w}, hB, a1);
        }
        // REG-stream phase: pairs 56..63, h quads 28..31
#pragma unroll
        for (int k = 0; k < 4; ++k) {
            float4 hq = hb4[28 + k];
            f32x2 hA = (f32x2){hq.x, hq.y}, hB = (f32x2){hq.z, hq.w};
            a0 = __builtin_elementwise_fma(s0[2 * k], hA, a0);
            a0 = __builtin_elementwise_fma(s0[2 * k + 1], hB, a0);
            a1 = __builtin_elementwise_fma(s1[2 * k], hA, a1);
            a1 = __builtin_elementwise_fma(s1[2 * k + 1], hB, a1);
        }
        float p0 = a0.x + a0.y, p1 = a1.x + a1.y;

        const unsigned tag = (unsigned)(s + 1);
        const size_t par = (size_t)(s & 1) << 10;   // parity offset (elements)
        if (!mine) {
            unsigned long long k0 =
                ((unsigned long long)tag << 32) | (unsigned long long)__float_as_uint(p0);
            unsigned long long k1 =
                ((unsigned long long)tag << 32) | (unsigned long long)__float_as_uint(p1);
            // fast path: two plain 8B stores, same 16B line (XCD L2)
            store_l2x2(fwb + par, k0, k1);
            // slow path: LLC-coherent packed atomics (placement-safe);
            // never waited on -- producers have no per-step vmcnt waits
            unsigned long long* sb = swb + par;
            __hip_atomic_store(sb, k0, __ATOMIC_RELAXED, __HIP_MEMORY_SCOPE_AGENT);
            __hip_atomic_store(sb + 1, k1, __ATOMIC_RELAXED, __HIP_MEMORY_SCOPE_AGENT);
        } else {
            const unsigned long long* fr = frb + par;
            const unsigned long long* sr = srb + par;
            float q0f, q1f;
            for (;;) {
                unsigned long long f0, f1;
                load_l2x2(fr, f0, f1);
                if ((unsigned)(f0 >> 32) == tag && (unsigned)(f1 >> 32) == tag) {
                    q0f = __uint_as_float((unsigned)f0);
                    q1f = __uint_as_float((unsigned)f1);
                    break;
                }
                unsigned long long a0q = __hip_atomic_load(
                    sr, __ATOMIC_RELAXED, __HIP_MEMORY_SCOPE_AGENT);
                unsigned long long a1q = __hip_atomic_load(
                    sr + 1, __ATOMIC_RELAXED, __HIP_MEMORY_SCOPE_AGENT);
                if ((unsigned)(a0q >> 32) == tag && (unsigned)(a1q >> 32) == tag) {
                    q0f = __uint_as_float((unsigned)a0q);
                    q1f = __uint_as_float((unsigned)a1q);
                    break;
                }
            }
            float g0 = p0 + q0f + bias0 + x0;
            float g1 = p1 + q1f + bias1 + x1;
            // half 0: g0=i-gate, g1=g-gate; half 1: g0=f-gate, g1=o-gate
            float e0 = sigmoid_fast(g0);
            float u, v;
            if (half == 0) { u = e0 * fast_tanh(g1); v = 0.f; }  // u = i*g
            else           { u = e0; v = sigmoid_fast(g1); }     // u = f, v = o
            float fx = __shfl_xor(u, 32);   // lanes<32 receive f
            float ox = __shfl_xor(v, 32);   // lanes<32 receive o
            if (half == 0) {
                c = fx * c + u;
                float h = ox * fast_tanh(c);
                h_sh[(s + 1) & 1][(qw << 5) + li] = h;
                int orow = dir ? srow : s;
                enc[((size_t)b * S_ + orow) * 512 + dir * H_ + base + (qw << 5) + li] =
                    (orow < len) ? h : 0.f;
            }
        }
        // ONE barrier per step, LDS-only wait: h(s+1) published; no vmcnt drain
        barrier_lds();

        srow = srow_n;
        x0 = x0n; x1 = x1n;
    }
}

// ---------------------------------------------------------------------------
// K3: U = enc@Ua^T, W = enc@Wa^T  (r12: grid (8,64), 16 rows/block)
// ---------------------------------------------------------------------------
__global__ __launch_bounds__(256) void uw_kernel(
    const float* __restrict__ enc, const float* __restrict__ Ua,
    const float* __restrict__ Wa, float* __restrict__ U, float* __restrict__ Wout) {
    __shared__ float wgt[60][129];
    __shared__ float erow[4][128];
    const int tid = threadIdx.x;
    const int b = blockIdx.y, s0 = blockIdx.x * 16;
    const int rl = tid >> 6;
    const int d = tid & 63;
    const int dd = d & 31;
    const int isW = d >> 5;
    float acc[4];
#pragma unroll
    for (int i = 0; i < 4; ++i) acc[i] = 0.f;

    for (int kk = 0; kk < 4; ++kk) {
        __syncthreads();
        for (int i = tid; i < 30 * 128; i += 256) {
            int r = i >> 7, k = i & 127;
            wgt[r][k] = Ua[(size_t)r * 512 + kk * 128 + k];
            wgt[r + 30][k] = Wa[(size_t)r * 512 + kk * 128 + k];
        }
        for (int chunk = 0; chunk < 4; ++chunk) {
            __syncthreads();
            for (int i = tid; i < 4 * 128; i += 256) {
                int r = i >> 7, k = i & 127;
                erow[r][k] = enc[((size_t)b * S_ + (s0 + chunk * 4 + r)) * 512 + kk * 128 + k];
            }
            __syncthreads();
            if (dd < HID_) {
                const float* wr = wgt[dd + 30 * isW];
                const float* er = erow[rl];
                float a = acc[chunk];
#pragma unroll
                for (int k = 0; k < 128; ++k) a = fmaf(er[k], wr[k], a);
                acc[chunk] = a;
            }
        }
    }
    if (dd < HID_) {
        float* dst = isW ? Wout : U;
#pragma unroll
        for (int chunk = 0; chunk < 4; ++chunk)
            dst[((size_t)b * S_ + (s0 + chunk * 4 + rl)) * 32 + dd] = acc[chunk];
    }
}

// ---------------------------------------------------------------------------
// K4: scores + predictions  (r12: grid (8,64), 16 i-rows/block)
// ---------------------------------------------------------------------------
__global__ __launch_bounds__(256) void scores_kernel(
    const float* __restrict__ U, const float* __restrict__ W,
    const float* __restrict__ va,
    float* __restrict__ scores, float* __restrict__ preds) {
    __shared__ float w_sh[128][31];
    const int b = blockIdx.y, i0 = blockIdx.x * 16;
    const int tid = threadIdx.x;

    float va_r[HID_];
#pragma unroll
    for (int d2 = 0; d2 < HID_; ++d2) va_r[d2] = va[d2];

    for (int i = tid; i < 128 * HID_; i += 256) {
        int r = i / HID_, d2 = i - r * HID_;
        w_sh[r][d2] = W[((size_t)b * S_ + r) * 32 + d2];
    }
    __syncthreads();

    const int il = tid >> 4;            // 0..15
    const int jb = (tid & 15) * 8;      // 0..120
    float u_r[HID_];
    const float* urow = U + ((size_t)b * S_ + i0 + il) * 32;
#pragma unroll
    for (int d2 = 0; d2 < HID_; ++d2) u_r[d2] = urow[d2];

    const size_t obase = ((size_t)b * S_ + (i0 + il)) * S_;
    for (int jj = 0; jj < 8; ++jj) {
        int j = jb + jj;
        float acc = 0.f;
#pragma unroll
        for (int d2 = 0; d2 < HID_; ++d2)
            acc = fmaf(va_r[d2], fast_tanh(u_r[d2] + w_sh[j][d2]), acc);
        scores[obase + j] = acc;
        preds[obase + j] = (sigmoid_acc(acc) >= 0.5f) ? 1.f : 0.f;
    }
}

// ---------------------------------------------------------------------------
// Workspace layout (bytes):
//   Xg     @ 0          : 2*8192*1024*4 = 67,108,864
//   enc    @ 67,108,864 : 64*128*512*4  = 16,777,216  (ALIASED: embF16
//                         16,384,000B lives here during prep+gemm2; lstm
//                         overwrites it afterwards -- stream-ordered)
//   U      @ 83,886,080 : 8192*32*4     =  1,048,576  (ALIASED: WihF16
//                         1,048,576B during prep+gemm2; uw overwrites after)
//   W      @ 84,934,656 : 8192*32*4     =  1,048,576
//   Fch    @ 85,983,232 : 128*2*2*512*8 =  2,097,152
//   Sch    @ 88,080,384 : 128*2*2*512*8 =  2,097,152
//   sT     @ 90,177,536 : 16*1024*16    =    262,144   (total ~90.4 MB)
// ---------------------------------------------------------------------------
extern "C" void kernel_launch(void* const* d_in, const int* in_sizes, int n_in,
                              void* d_out, int out_size, void* d_ws, size_t ws_size,
                              hipStream_t stream) {
    (void)in_sizes; (void)n_in; (void)out_size; (void)ws_size;
    const int* concepts = (const int*)d_in[0];
    const int* lens = (const int*)d_in[1];
    const float* embedding = (const float*)d_in[2];
    const float* Wih_f = (const float*)d_in[3];
    const float* Whh_f = (const float*)d_in[4];
    const float* b_f = (const float*)d_in[5];
    const float* Wih_b = (const float*)d_in[6];
    const float* Whh_b = (const float*)d_in[7];
    const float* b_b = (const float*)d_in[8];
    const float* Ua = (const float*)d_in[9];
    const float* Wa = (const float*)d_in[10];
    const float* va = (const float*)d_in[11];

    char* ws = (char*)d_ws;
    float* Xg = (float*)(ws + 0);
    float* enc = (float*)(ws + 67108864);
    float* U = (float*)(ws + 83886080);
    float* W = (float*)(ws + 84934656);
    unsigned long long* Fch = (unsigned long long*)(ws + 85983232);
    unsigned long long* Sch = (unsigned long long*)(ws + 88080384);
    float4* sT = (float4*)(ws + 90177536);
    _Float16* embF16 = (_Float16*)(ws + 67108864);   // aliases enc
    _Float16* WihF16 = (_Float16*)(ws + 83886080);   // aliases U

    float* scores = (float*)d_out;
    float* preds = scores + (size_t)B_ * S_ * S_;

    hipLaunchKernelGGL(prep_stream_kernel, dim3(256), dim3(256), 0, stream,
                       Whh_f, Whh_b, embedding, Wih_f, Wih_b, sT, Fch,
                       embF16, WihF16);
    hipLaunchKernelGGL(gemm2_kernel, dim3(512, 2), dim3(256), 0, stream,
                       concepts, embF16, WihF16, Xg);

    {
        const float* XgA = Xg;
        void* ka[] = {(void*)&XgA, (void*)&Whh_f, (void*)&Whh_b, (void*)&b_f,
                      (void*)&b_b, (void*)&lens, (void*)&enc, (void*)&Fch,
                      (void*)&Sch, (void*)&sT};
        (void)hipLaunchCooperativeKernel((const void*)lstm_ks3_kernel, dim3(256),
                                         dim3(512), ka,
                                         LPD_ * 512 * sizeof(float4), stream);
    }

    hipLaunchKernelGGL(uw_kernel, dim3(8, 64), dim3(256), 0, stream,
                       enc, Ua, Wa, U, W);
    hipLaunchKernelGGL(scores_kernel, dim3(8, 64), dim3(256), 0, stream,
                       U, W, va, scores, preds);
}